// Round 6
// baseline (585.203 us; speedup 1.0000x reference)
//
#include <hip/hip_runtime.h>
#include <stdint.h>

#define NN 50000
#define NE 800000
#define LN_EPS 1e-5f
#define NBLK 196  // ceil(NN/256)

typedef __attribute__((ext_vector_type(8))) __bf16 bf16x8;
typedef __attribute__((ext_vector_type(4))) float floatx4;

#define GLD_LDS16(gp, lp)                                              \
  __builtin_amdgcn_global_load_lds(                                    \
      (const __attribute__((address_space(1))) unsigned int*)(gp),     \
      (__attribute__((address_space(3))) unsigned int*)(lp), 16, 0, 0)

__device__ __forceinline__ float bfbits2f(unsigned short u) {
  return __uint_as_float(((unsigned)u) << 16);
}
__device__ __forceinline__ unsigned short f2bfbits(float f) {
  unsigned u = __float_as_uint(f);
  u += 0x7FFFu + ((u >> 16) & 1u);   // round-to-nearest-even
  return (unsigned short)(u >> 16);
}
__device__ __forceinline__ float4 ld4f(const void* p, size_t i, bool f32) {
  if (f32) return *reinterpret_cast<const float4*>((const float*)p + i);
  ushort4 r = *reinterpret_cast<const ushort4*>((const unsigned short*)p + i);
  return make_float4(bfbits2f(r.x), bfbits2f(r.y), bfbits2f(r.z), bfbits2f(r.w));
}
__device__ __forceinline__ float ld1f(const void* p, size_t i, bool f32) {
  return f32 ? ((const float*)p)[i] : bfbits2f(((const unsigned short*)p)[i]);
}

// fp32 vs bf16 input detection (fp32 read as bf16 halves -> huge/NaN values).
__global__ void detect_kernel(const void* feat, int* flag) {
  int cnt = 0;
  const unsigned short* u = (const unsigned short*)feat;
  for (int i = threadIdx.x; i < 512; i += 64) {
    float v = bfbits2f(u[i]);
    if (!(fabsf(v) < 1e6f)) cnt++;
  }
#pragma unroll
  for (int off = 32; off > 0; off >>= 1) cnt += __shfl_down(cnt, off, 64);
  if (threadIdx.x == 0) flag[0] = (cnt > 8) ? 1 : 0;
}

__global__ void conv_feat_kernel(const void* __restrict__ feat,
                                 unsigned short* __restrict__ featbf,
                                 const int* __restrict__ flag) {
  bool f32 = flag[0] != 0;
  size_t i = ((size_t)blockIdx.x * blockDim.x + threadIdx.x) * 4;
  float4 v = ld4f(feat, i, f32);
  ushort4 o = {f2bfbits(v.x), f2bfbits(v.y), f2bfbits(v.z), f2bfbits(v.w)};
  *reinterpret_cast<ushort4*>(featbf + i) = o;
}

// Bt[n][k] bf16, n in [0,2D): n<D -> Ws[k][n], else Wn[k][n-D]. K=256.
template <int D>
__global__ void conv_w_kernel(const void* __restrict__ wself,
                              const void* __restrict__ wneigh,
                              unsigned short* __restrict__ Bt,
                              const int* __restrict__ flag) {
  bool f32 = flag[0] != 0;
  int t = blockIdx.x * blockDim.x + threadIdx.x;  // 2D*256
  int k = t & 255, n = t >> 8;
  float v = (n < D) ? ld1f(wself, (size_t)k * D + n, f32)
                    : ld1f(wneigh, (size_t)k * D + (n - D), f32);
  Bt[t] = f2bfbits(v);
}

// ---- CSR build ----
__global__ void count_kernel(const int* __restrict__ dst, int* __restrict__ counts) {
  int e = blockIdx.x * blockDim.x + threadIdx.x;
  if (e >= NE) return;
  atomicAdd(&counts[dst[e]], 1);
}

__global__ __launch_bounds__(256) void bsum_kernel(const int* __restrict__ counts,
                                                   int* __restrict__ bsum) {
  int i = blockIdx.x * 256 + threadIdx.x;
  int v = (i < NN) ? counts[i] : 0;
#pragma unroll
  for (int off = 32; off > 0; off >>= 1) v += __shfl_down(v, off, 64);
  __shared__ int w[4];
  if ((threadIdx.x & 63) == 0) w[threadIdx.x >> 6] = v;
  __syncthreads();
  if (threadIdx.x == 0) bsum[blockIdx.x] = w[0] + w[1] + w[2] + w[3];
}

__global__ __launch_bounds__(256) void bscan_kernel(const int* __restrict__ bsum,
                                                    int* __restrict__ boff) {
  __shared__ int sh[256];
  int tid = threadIdx.x;
  int v = (tid < NBLK) ? bsum[tid] : 0;
  sh[tid] = v;
  __syncthreads();
  for (int off = 1; off < 256; off <<= 1) {
    int t = (tid >= off) ? sh[tid - off] : 0;
    __syncthreads();
    sh[tid] += t;
    __syncthreads();
  }
  boff[tid] = sh[tid] - v;
}

__global__ __launch_bounds__(256) void rowptr_kernel(const int* __restrict__ counts,
                                                     const int* __restrict__ boff,
                                                     int* __restrict__ rowptr,
                                                     int* __restrict__ cursor) {
  __shared__ int sh[256];
  int tid = threadIdx.x;
  int i = blockIdx.x * 256 + tid;
  int v = (i < NN) ? counts[i] : 0;
  sh[tid] = v;
  __syncthreads();
  for (int off = 1; off < 256; off <<= 1) {
    int t = (tid >= off) ? sh[tid - off] : 0;
    __syncthreads();
    sh[tid] += t;
    __syncthreads();
  }
  int incl = sh[tid];
  int base = boff[blockIdx.x];
  if (i < NN) {
    int r = base + incl - v;
    rowptr[i] = r;
    cursor[i] = r;
  }
  if (i == NN - 1) rowptr[NN] = base + incl;
}

__global__ void fill_kernel(const int* __restrict__ src, const int* __restrict__ dst,
                            int* __restrict__ cursor, int* __restrict__ csr_src) {
  int e = blockIdx.x * blockDim.x + threadIdx.x;
  if (e >= NE) return;
  int pos = atomicAdd(&cursor[dst[e]], 1);
  csr_src[pos] = src[e];
}

// ---- MFMA GEMM: [Yself|Yn] = A(bf16 NNx256) @ Bt^T + [bias|0] ----
// 128x128 tile, BK=32, global_load_lds staging, LDS layout [kgroup][row][8].
template <int TWO_D>
__global__ __launch_bounds__(256) void gemm_pack_kernel(
    const unsigned short* __restrict__ A, const unsigned short* __restrict__ Bt,
    const void* __restrict__ bias, float* __restrict__ Yself,
    unsigned short* __restrict__ Yn, const int* __restrict__ dtflag) {
  constexpr int D = TWO_D / 2;
  __shared__ unsigned short As[512 * 8];  // 8 KB
  __shared__ unsigned short Bs[512 * 8];
  const int tid = threadIdx.x;
  const int lane = tid & 63;
  const int wave = tid >> 6;
  const int row0 = blockIdx.x * 128;
  const int col0 = blockIdx.y * 128;
  const int wr = (wave >> 1) * 64;
  const int wc = (wave & 1) * 64;
  const int fr = lane & 15;
  const int q = lane >> 4;

  floatx4 acc[4][4];
#pragma unroll
  for (int i = 0; i < 4; ++i)
#pragma unroll
    for (int j = 0; j < 4; ++j) acc[i][j] = (floatx4){0.f, 0.f, 0.f, 0.f};

  // slot s (0..511) <-> (kg=s>>7, row=s&127); LDS offset s*16B; wave-contiguous.
  const int srow = tid & 127;
  const int skg = tid >> 7;  // 0/1 (batch0), +2 (batch1)
  const size_t ga0 = (size_t)(row0 + srow) * 256 + skg * 8;
  const size_t gb0 = (size_t)(col0 + srow) * 256 + skg * 8;
  unsigned short* la0 = As + ((tid & 192) + 0) * 8;
  unsigned short* la1 = As + ((tid & 192) + 256) * 8;
  unsigned short* lb0 = Bs + ((tid & 192) + 0) * 8;
  unsigned short* lb1 = Bs + ((tid & 192) + 256) * 8;

  for (int kb = 0; kb < 256; kb += 32) {
    if (kb) __syncthreads();
    GLD_LDS16(A + ga0 + kb, la0);
    GLD_LDS16(A + ga0 + kb + 16, la1);  // kg+2
    GLD_LDS16(Bt + gb0 + kb, lb0);
    GLD_LDS16(Bt + gb0 + kb + 16, lb1);
    __syncthreads();
    bf16x8 af[4], bfr[4];
#pragma unroll
    for (int i = 0; i < 4; ++i)
      af[i] = *reinterpret_cast<const bf16x8*>(As + q * 1024 + (wr + i * 16 + fr) * 8);
#pragma unroll
    for (int j = 0; j < 4; ++j)
      bfr[j] = *reinterpret_cast<const bf16x8*>(Bs + q * 1024 + (wc + j * 16 + fr) * 8);
#pragma unroll
    for (int i = 0; i < 4; ++i)
#pragma unroll
      for (int j = 0; j < 4; ++j)
        acc[i][j] = __builtin_amdgcn_mfma_f32_16x16x32_bf16(af[i], bfr[j], acc[i][j], 0, 0, 0);
  }

  bool inf32 = dtflag[0] != 0;
#pragma unroll
  for (int j = 0; j < 4; ++j) {
    int gc = col0 + wc + j * 16 + fr;  // [0, TWO_D)
    bool self = gc < D;
    float bj = self ? ld1f(bias, gc, inf32) : 0.f;
#pragma unroll
    for (int i = 0; i < 4; ++i) {
      int rbase = row0 + wr + i * 16 + (lane >> 4) * 4;
#pragma unroll
      for (int r = 0; r < 4; ++r) {
        int gr = rbase + r;
        if (gr < NN) {
          float v = acc[i][j][r] + bj;
          if (self)
            Yself[(size_t)gr * D + gc] = v;
          else
            Yn[(size_t)gr * D + gc - D] = f2bfbits(v);
        }
      }
    }
  }
}

// ---- fused: h = ReLU(LN(Yself + mean(Yn[nbrs]))), D=256, one wave/row ----
__global__ __launch_bounds__(256) void fused_ln_kernel(
    const unsigned short* __restrict__ Yn, const float* __restrict__ Yself,
    const int* __restrict__ rowptr, const int* __restrict__ csr_src,
    const void* __restrict__ indeg, const void* __restrict__ g,
    const void* __restrict__ be, unsigned short* __restrict__ out,
    const int* __restrict__ dtflag) {
  bool inf32 = dtflag[0] != 0;
  int row = blockIdx.x * 4 + (threadIdx.x >> 6);
  int lane = threadIdx.x & 63;
  int half = lane >> 5;
  int l32 = lane & 31;
  int beg = rowptr[row], end = rowptr[row + 1];
  float a[8] = {};
  int e = beg + half;
  for (; e + 2 < end; e += 4) {
    int s0 = csr_src[e], s1 = csr_src[e + 2];
    uint4 r0 = *reinterpret_cast<const uint4*>(Yn + (size_t)s0 * 256 + l32 * 8);
    uint4 r1 = *reinterpret_cast<const uint4*>(Yn + (size_t)s1 * 256 + l32 * 8);
    const unsigned* u0 = &r0.x;
    const unsigned* u1 = &r1.x;
#pragma unroll
    for (int k = 0; k < 4; ++k) {
      a[2 * k] += bfbits2f((unsigned short)(u0[k] & 0xffff)) +
                  bfbits2f((unsigned short)(u1[k] & 0xffff));
      a[2 * k + 1] += bfbits2f((unsigned short)(u0[k] >> 16)) +
                      bfbits2f((unsigned short)(u1[k] >> 16));
    }
  }
  if (e < end) {
    int s0 = csr_src[e];
    uint4 r0 = *reinterpret_cast<const uint4*>(Yn + (size_t)s0 * 256 + l32 * 8);
    const unsigned* u0 = &r0.x;
#pragma unroll
    for (int k = 0; k < 4; ++k) {
      a[2 * k] += bfbits2f((unsigned short)(u0[k] & 0xffff));
      a[2 * k + 1] += bfbits2f((unsigned short)(u0[k] >> 16));
    }
  }
#pragma unroll
  for (int k = 0; k < 8; ++k) a[k] += __shfl_xor(a[k], 32, 64);
  // both halves now hold full sums for cols l32*8..+7
  float rd = 1.0f / ld1f(indeg, row, inf32);
  float4 y0 = *reinterpret_cast<const float4*>(Yself + (size_t)row * 256 + l32 * 8);
  float4 y1 = *reinterpret_cast<const float4*>(Yself + (size_t)row * 256 + l32 * 8 + 4);
  float vals[8];
  vals[0] = a[0] * rd + y0.x; vals[1] = a[1] * rd + y0.y;
  vals[2] = a[2] * rd + y0.z; vals[3] = a[3] * rd + y0.w;
  vals[4] = a[4] * rd + y1.x; vals[5] = a[5] * rd + y1.y;
  vals[6] = a[6] * rd + y1.z; vals[7] = a[7] * rd + y1.w;
  float s = 0.f, sq = 0.f;
#pragma unroll
  for (int k = 0; k < 8; ++k) { s += vals[k]; sq += vals[k] * vals[k]; }
#pragma unroll
  for (int off = 1; off < 32; off <<= 1) {
    s += __shfl_xor(s, off, 64);
    sq += __shfl_xor(sq, off, 64);
  }
  float mu = s * (1.0f / 256.0f);
  float var = fmaxf(sq * (1.0f / 256.0f) - mu * mu, 0.0f);
  float rs = rsqrtf(var + LN_EPS);
  if (half == 0) {
    uint4 o;
    unsigned* ou = &o.x;
#pragma unroll
    for (int k = 0; k < 4; ++k) {
      int c = l32 * 8 + 2 * k;
      float x0 = (vals[2 * k] - mu) * rs * ld1f(g, c, inf32) + ld1f(be, c, inf32);
      float x1 = (vals[2 * k + 1] - mu) * rs * ld1f(g, c + 1, inf32) + ld1f(be, c + 1, inf32);
      unsigned lo = f2bfbits(fmaxf(x0, 0.0f));
      unsigned hi = f2bfbits(fmaxf(x1, 0.0f));
      ou[k] = lo | (hi << 16);
    }
    *reinterpret_cast<uint4*>(out + (size_t)row * 256 + l32 * 8) = o;
  }
}

// ---- fused final: d_out = Yself + mean(Yn[nbrs]); D=128, quarter-wave gather ----
__global__ __launch_bounds__(256) void fused_out_kernel(
    const unsigned short* __restrict__ Yn, const float* __restrict__ Yself,
    const int* __restrict__ rowptr, const int* __restrict__ csr_src,
    const void* __restrict__ indeg, void* __restrict__ out,
    const int* __restrict__ dtflag) {
  bool inf32 = dtflag[0] != 0;
  int row = blockIdx.x * 4 + (threadIdx.x >> 6);
  int lane = threadIdx.x & 63;
  int qq = lane >> 4;
  int l16 = lane & 15;
  int beg = rowptr[row], end = rowptr[row + 1];
  float a[8] = {};
  for (int e = beg + qq; e < end; e += 4) {
    int s0 = csr_src[e];
    uint4 r0 = *reinterpret_cast<const uint4*>(Yn + (size_t)s0 * 128 + l16 * 8);
    const unsigned* u0 = &r0.x;
#pragma unroll
    for (int k = 0; k < 4; ++k) {
      a[2 * k] += bfbits2f((unsigned short)(u0[k] & 0xffff));
      a[2 * k + 1] += bfbits2f((unsigned short)(u0[k] >> 16));
    }
  }
#pragma unroll
  for (int k = 0; k < 8; ++k) {
    a[k] += __shfl_xor(a[k], 16, 64);
    a[k] += __shfl_xor(a[k], 32, 64);
  }
  if (qq == 0) {
    float rd = 1.0f / ld1f(indeg, row, inf32);
    size_t base = (size_t)row * 128 + l16 * 8;
    float4 y0 = *reinterpret_cast<const float4*>(Yself + base);
    float4 y1 = *reinterpret_cast<const float4*>(Yself + base + 4);
    float v[8] = {a[0] * rd + y0.x, a[1] * rd + y0.y, a[2] * rd + y0.z,
                  a[3] * rd + y0.w, a[4] * rd + y1.x, a[5] * rd + y1.y,
                  a[6] * rd + y1.z, a[7] * rd + y1.w};
    if (inf32) {
      float4 o0 = {v[0], v[1], v[2], v[3]};
      float4 o1 = {v[4], v[5], v[6], v[7]};
      *reinterpret_cast<float4*>((float*)out + base) = o0;
      *reinterpret_cast<float4*>((float*)out + base + 4) = o1;
    } else {
      uint4 o;
      unsigned* ou = &o.x;
#pragma unroll
      for (int k = 0; k < 4; ++k)
        ou[k] = (unsigned)f2bfbits(v[2 * k]) | ((unsigned)f2bfbits(v[2 * k + 1]) << 16);
      *reinterpret_cast<uint4*>((unsigned short*)out + base) = o;
    }
  }
}

extern "C" void kernel_launch(void* const* d_in, const int* in_sizes, int n_in,
                              void* d_out, int out_size, void* d_ws, size_t ws_size,
                              hipStream_t stream) {
  const void* feat = d_in[0];
  const int* ei = (const int*)d_in[1];
  const void* indeg = d_in[2];
  const void* ws0 = d_in[3]; const void* wn0 = d_in[4]; const void* b0 = d_in[5];
  const void* ws1 = d_in[6]; const void* wn1 = d_in[7]; const void* b1 = d_in[8];
  const void* ws2 = d_in[9]; const void* wn2 = d_in[10]; const void* b2 = d_in[11];
  const void* g0 = d_in[12]; const void* be0 = d_in[13];
  const void* g1 = d_in[14]; const void* be1 = d_in[15];
  const int* src = ei;
  const int* dst = ei + NE;

  unsigned short* featbf = (unsigned short*)d_ws;            // 25.6 MB
  unsigned short* hbf = featbf + (size_t)NN * 256;           // 25.6 MB
  unsigned short* Yn = hbf + (size_t)NN * 256;               // 25.6 MB
  float* Yself = (float*)(Yn + (size_t)NN * 256);            // 51.2 MB
  unsigned short* Bt0 = (unsigned short*)(Yself + (size_t)NN * 256);
  unsigned short* Bt1 = Bt0 + 512 * 256;
  unsigned short* Bt2 = Bt1 + 512 * 256;
  int* flag = (int*)(Bt2 + 256 * 256);
  int* bsum = flag + 4;
  int* boff = bsum + 256;
  int* counts = boff + 256;
  int* rowptr = counts + NN;
  int* cursor = rowptr + NN + 1;
  int* csr_src = cursor + NN;

  dim3 blk(256);
  dim3 gE((NE + 255) / 256);
  dim3 gRow(12500);

  detect_kernel<<<1, 64, 0, stream>>>(feat, flag);
  conv_feat_kernel<<<12500, blk, 0, stream>>>(feat, featbf, flag);
  conv_w_kernel<256><<<512, blk, 0, stream>>>(ws0, wn0, Bt0, flag);
  conv_w_kernel<256><<<512, blk, 0, stream>>>(ws1, wn1, Bt1, flag);
  conv_w_kernel<128><<<256, blk, 0, stream>>>(ws2, wn2, Bt2, flag);

  hipMemsetAsync(counts, 0, NN * sizeof(int), stream);
  count_kernel<<<gE, blk, 0, stream>>>(dst, counts);
  bsum_kernel<<<NBLK, blk, 0, stream>>>(counts, bsum);
  bscan_kernel<<<1, blk, 0, stream>>>(bsum, boff);
  rowptr_kernel<<<NBLK, blk, 0, stream>>>(counts, boff, rowptr, cursor);
  fill_kernel<<<gE, blk, 0, stream>>>(src, dst, cursor, csr_src);

  // layer 0
  gemm_pack_kernel<512><<<dim3(391, 4), blk, 0, stream>>>(featbf, Bt0, b0, Yself, Yn, flag);
  fused_ln_kernel<<<gRow, blk, 0, stream>>>(Yn, Yself, rowptr, csr_src, indeg, g0, be0, hbf, flag);
  // layer 1
  gemm_pack_kernel<512><<<dim3(391, 4), blk, 0, stream>>>(hbf, Bt1, b1, Yself, Yn, flag);
  fused_ln_kernel<<<gRow, blk, 0, stream>>>(Yn, Yself, rowptr, csr_src, indeg, g1, be1, hbf, flag);
  // layer 2 -> d_out
  gemm_pack_kernel<256><<<dim3(391, 2), blk, 0, stream>>>(hbf, Bt2, b2, Yself, Yn, flag);
  fused_out_kernel<<<gRow, blk, 0, stream>>>(Yn, Yself, rowptr, csr_src, indeg, d_out, flag);
}

// Round 7
// 561.719 us; speedup vs baseline: 1.0418x; 1.0418x over previous
//
#include <hip/hip_runtime.h>
#include <stdint.h>

#define NN 50000
#define NE 800000
#define LN_EPS 1e-5f
#define NBLK 196  // ceil(NN/256)

typedef __attribute__((ext_vector_type(8))) __bf16 bf16x8;
typedef __attribute__((ext_vector_type(4))) float floatx4;

#define GLD_LDS16(gp, lp)                                              \
  __builtin_amdgcn_global_load_lds(                                    \
      (const __attribute__((address_space(1))) unsigned int*)(gp),     \
      (__attribute__((address_space(3))) unsigned int*)(lp), 16, 0, 0)

__device__ __forceinline__ float bfbits2f(unsigned short u) {
  return __uint_as_float(((unsigned)u) << 16);
}
__device__ __forceinline__ unsigned short f2bfbits(float f) {
  unsigned u = __float_as_uint(f);
  u += 0x7FFFu + ((u >> 16) & 1u);   // round-to-nearest-even
  return (unsigned short)(u >> 16);
}
__device__ __forceinline__ float4 ld4f(const void* p, size_t i, bool f32) {
  if (f32) return *reinterpret_cast<const float4*>((const float*)p + i);
  ushort4 r = *reinterpret_cast<const ushort4*>((const unsigned short*)p + i);
  return make_float4(bfbits2f(r.x), bfbits2f(r.y), bfbits2f(r.z), bfbits2f(r.w));
}
__device__ __forceinline__ float ld1f(const void* p, size_t i, bool f32) {
  return f32 ? ((const float*)p)[i] : bfbits2f(((const unsigned short*)p)[i]);
}

// fp32 vs bf16 input detection (fp32 read as bf16 halves -> huge/NaN values).
__global__ void detect_kernel(const void* feat, int* flag) {
  int cnt = 0;
  const unsigned short* u = (const unsigned short*)feat;
  for (int i = threadIdx.x; i < 512; i += 64) {
    float v = bfbits2f(u[i]);
    if (!(fabsf(v) < 1e6f)) cnt++;
  }
#pragma unroll
  for (int off = 32; off > 0; off >>= 1) cnt += __shfl_down(cnt, off, 64);
  if (threadIdx.x == 0) flag[0] = (cnt > 8) ? 1 : 0;
}

__global__ void conv_feat_kernel(const void* __restrict__ feat,
                                 unsigned short* __restrict__ featbf,
                                 const int* __restrict__ flag) {
  bool f32 = flag[0] != 0;
  size_t i = ((size_t)blockIdx.x * blockDim.x + threadIdx.x) * 4;
  float4 v = ld4f(feat, i, f32);
  ushort4 o = {f2bfbits(v.x), f2bfbits(v.y), f2bfbits(v.z), f2bfbits(v.w)};
  *reinterpret_cast<ushort4*>(featbf + i) = o;
}

// Bt[n][k] bf16, n in [0,2D): n<D -> Ws[k][n], else Wn[k][n-D]. K=256.
template <int D>
__global__ void conv_w_kernel(const void* __restrict__ wself,
                              const void* __restrict__ wneigh,
                              unsigned short* __restrict__ Bt,
                              const int* __restrict__ flag) {
  bool f32 = flag[0] != 0;
  int t = blockIdx.x * blockDim.x + threadIdx.x;  // 2D*256
  int k = t & 255, n = t >> 8;
  float v = (n < D) ? ld1f(wself, (size_t)k * D + n, f32)
                    : ld1f(wneigh, (size_t)k * D + (n - D), f32);
  Bt[t] = f2bfbits(v);
}

// ---- CSR build ----
__global__ void count_kernel(const int* __restrict__ dst, int* __restrict__ counts) {
  int e = blockIdx.x * blockDim.x + threadIdx.x;
  if (e >= NE) return;
  atomicAdd(&counts[dst[e]], 1);
}

__global__ __launch_bounds__(256) void bsum_kernel(const int* __restrict__ counts,
                                                   int* __restrict__ bsum) {
  int i = blockIdx.x * 256 + threadIdx.x;
  int v = (i < NN) ? counts[i] : 0;
#pragma unroll
  for (int off = 32; off > 0; off >>= 1) v += __shfl_down(v, off, 64);
  __shared__ int w[4];
  if ((threadIdx.x & 63) == 0) w[threadIdx.x >> 6] = v;
  __syncthreads();
  if (threadIdx.x == 0) bsum[blockIdx.x] = w[0] + w[1] + w[2] + w[3];
}

__global__ __launch_bounds__(256) void bscan_kernel(const int* __restrict__ bsum,
                                                    int* __restrict__ boff) {
  __shared__ int sh[256];
  int tid = threadIdx.x;
  int v = (tid < NBLK) ? bsum[tid] : 0;
  sh[tid] = v;
  __syncthreads();
  for (int off = 1; off < 256; off <<= 1) {
    int t = (tid >= off) ? sh[tid - off] : 0;
    __syncthreads();
    sh[tid] += t;
    __syncthreads();
  }
  boff[tid] = sh[tid] - v;
}

__global__ __launch_bounds__(256) void rowptr_kernel(const int* __restrict__ counts,
                                                     const int* __restrict__ boff,
                                                     int* __restrict__ rowptr,
                                                     int* __restrict__ cursor) {
  __shared__ int sh[256];
  int tid = threadIdx.x;
  int i = blockIdx.x * 256 + tid;
  int v = (i < NN) ? counts[i] : 0;
  sh[tid] = v;
  __syncthreads();
  for (int off = 1; off < 256; off <<= 1) {
    int t = (tid >= off) ? sh[tid - off] : 0;
    __syncthreads();
    sh[tid] += t;
    __syncthreads();
  }
  int incl = sh[tid];
  int base = boff[blockIdx.x];
  if (i < NN) {
    int r = base + incl - v;
    rowptr[i] = r;
    cursor[i] = r;
  }
  if (i == NN - 1) rowptr[NN] = base + incl;
}

__global__ void fill_kernel(const int* __restrict__ src, const int* __restrict__ dst,
                            int* __restrict__ cursor, int* __restrict__ csr_src) {
  int e = blockIdx.x * blockDim.x + threadIdx.x;
  if (e >= NE) return;
  int pos = atomicAdd(&cursor[dst[e]], 1);
  csr_src[pos] = src[e];
}

// ---- MFMA GEMM: [Yself|Yn] = A(bf16 NNx256) @ Bt^T + [bias|0] ----
// 128x128 tile, BK=32. global_load_lds staging, coalesced lanes:
// slot s (16B) <-> row=s>>2, slot-chunk=s&3; GLOBAL chunk = (s&3)^((s>>3)&3).
// -> 4 consecutive lanes cover one 64B global segment (coalesced);
// -> frag ds_read_b128 at slot-chunk q^((fr>>1)&3): 8-lane phases hit all
//    32 banks (conflict-free).
template <int TWO_D>
__global__ __launch_bounds__(256) void gemm_pack_kernel(
    const unsigned short* __restrict__ A, const unsigned short* __restrict__ Bt,
    const void* __restrict__ bias, float* __restrict__ Yself,
    unsigned short* __restrict__ Yn, const int* __restrict__ dtflag) {
  constexpr int D = TWO_D / 2;
  __shared__ unsigned short As[128 * 32];  // 8 KB
  __shared__ unsigned short Bs[128 * 32];
  const int tid = threadIdx.x;
  const int lane = tid & 63;
  const int wave = tid >> 6;
  const int row0 = blockIdx.x * 128;
  const int col0 = blockIdx.y * 128;
  const int wr = (wave >> 1) * 64;
  const int wc = (wave & 1) * 64;
  const int fr = lane & 15;
  const int q = lane >> 4;
  const int sw = (q ^ ((fr >> 1) & 3)) * 8;  // swizzled chunk offset (ushorts)

  floatx4 acc[4][4];
#pragma unroll
  for (int i = 0; i < 4; ++i)
#pragma unroll
    for (int j = 0; j < 4; ++j) acc[i][j] = (floatx4){0.f, 0.f, 0.f, 0.f};

  // staging: thread tid handles slots tid and tid+256 for both A and B
  const int srow = tid >> 2;                          // 0..63
  const int gch = ((tid & 3) ^ ((tid >> 3) & 3)) * 8; // global chunk offset
  const size_t ga0 = (size_t)(row0 + srow) * 256 + gch;
  const size_t ga1 = (size_t)(row0 + srow + 64) * 256 + gch;
  const size_t gb0 = (size_t)(col0 + srow) * 256 + gch;
  const size_t gb1 = (size_t)(col0 + srow + 64) * 256 + gch;
  unsigned short* la0 = As + (tid & 192) * 8;           // wave-uniform bases
  unsigned short* la1 = As + ((tid & 192) + 256) * 8;
  unsigned short* lb0 = Bs + (tid & 192) * 8;
  unsigned short* lb1 = Bs + ((tid & 192) + 256) * 8;

  for (int kb = 0; kb < 256; kb += 32) {
    if (kb) __syncthreads();
    GLD_LDS16(A + ga0 + kb, la0);
    GLD_LDS16(A + ga1 + kb, la1);
    GLD_LDS16(Bt + gb0 + kb, lb0);
    GLD_LDS16(Bt + gb1 + kb, lb1);
    __syncthreads();
    bf16x8 af[4], bfr[4];
#pragma unroll
    for (int i = 0; i < 4; ++i)
      af[i] = *reinterpret_cast<const bf16x8*>(As + (wr + i * 16 + fr) * 32 + sw);
#pragma unroll
    for (int j = 0; j < 4; ++j)
      bfr[j] = *reinterpret_cast<const bf16x8*>(Bs + (wc + j * 16 + fr) * 32 + sw);
#pragma unroll
    for (int i = 0; i < 4; ++i)
#pragma unroll
      for (int j = 0; j < 4; ++j)
        acc[i][j] = __builtin_amdgcn_mfma_f32_16x16x32_bf16(af[i], bfr[j], acc[i][j], 0, 0, 0);
  }

  bool inf32 = dtflag[0] != 0;
#pragma unroll
  for (int j = 0; j < 4; ++j) {
    int gc = col0 + wc + j * 16 + fr;  // [0, TWO_D)
    bool self = gc < D;
    float bj = self ? ld1f(bias, gc, inf32) : 0.f;
#pragma unroll
    for (int i = 0; i < 4; ++i) {
      int rbase = row0 + wr + i * 16 + (lane >> 4) * 4;
#pragma unroll
      for (int r = 0; r < 4; ++r) {
        int gr = rbase + r;
        if (gr < NN) {
          float v = acc[i][j][r] + bj;
          if (self)
            Yself[(size_t)gr * D + gc] = v;
          else
            Yn[(size_t)gr * D + gc - D] = f2bfbits(v);
        }
      }
    }
  }
}

// ---- fused: h = ReLU(LN(Yself + mean(Yn[nbrs]))), D=256, one wave/row ----
__global__ __launch_bounds__(256) void fused_ln_kernel(
    const unsigned short* __restrict__ Yn, const float* __restrict__ Yself,
    const int* __restrict__ rowptr, const int* __restrict__ csr_src,
    const void* __restrict__ indeg, const void* __restrict__ g,
    const void* __restrict__ be, unsigned short* __restrict__ out,
    const int* __restrict__ dtflag) {
  bool inf32 = dtflag[0] != 0;
  int row = blockIdx.x * 4 + (threadIdx.x >> 6);
  int lane = threadIdx.x & 63;
  int half = lane >> 5;
  int l32 = lane & 31;
  int beg = rowptr[row], end = rowptr[row + 1];
  float a[8] = {};
  int e = beg + half;
  for (; e + 2 < end; e += 4) {
    int s0 = csr_src[e], s1 = csr_src[e + 2];
    uint4 r0 = *reinterpret_cast<const uint4*>(Yn + (size_t)s0 * 256 + l32 * 8);
    uint4 r1 = *reinterpret_cast<const uint4*>(Yn + (size_t)s1 * 256 + l32 * 8);
    const unsigned* u0 = &r0.x;
    const unsigned* u1 = &r1.x;
#pragma unroll
    for (int k = 0; k < 4; ++k) {
      a[2 * k] += bfbits2f((unsigned short)(u0[k] & 0xffff)) +
                  bfbits2f((unsigned short)(u1[k] & 0xffff));
      a[2 * k + 1] += bfbits2f((unsigned short)(u0[k] >> 16)) +
                      bfbits2f((unsigned short)(u1[k] >> 16));
    }
  }
  if (e < end) {
    int s0 = csr_src[e];
    uint4 r0 = *reinterpret_cast<const uint4*>(Yn + (size_t)s0 * 256 + l32 * 8);
    const unsigned* u0 = &r0.x;
#pragma unroll
    for (int k = 0; k < 4; ++k) {
      a[2 * k] += bfbits2f((unsigned short)(u0[k] & 0xffff));
      a[2 * k + 1] += bfbits2f((unsigned short)(u0[k] >> 16));
    }
  }
#pragma unroll
  for (int k = 0; k < 8; ++k) a[k] += __shfl_xor(a[k], 32, 64);
  float rd = 1.0f / ld1f(indeg, row, inf32);
  float4 y0 = *reinterpret_cast<const float4*>(Yself + (size_t)row * 256 + l32 * 8);
  float4 y1 = *reinterpret_cast<const float4*>(Yself + (size_t)row * 256 + l32 * 8 + 4);
  float vals[8];
  vals[0] = a[0] * rd + y0.x; vals[1] = a[1] * rd + y0.y;
  vals[2] = a[2] * rd + y0.z; vals[3] = a[3] * rd + y0.w;
  vals[4] = a[4] * rd + y1.x; vals[5] = a[5] * rd + y1.y;
  vals[6] = a[6] * rd + y1.z; vals[7] = a[7] * rd + y1.w;
  float s = 0.f, sq = 0.f;
#pragma unroll
  for (int k = 0; k < 8; ++k) { s += vals[k]; sq += vals[k] * vals[k]; }
#pragma unroll
  for (int off = 1; off < 32; off <<= 1) {
    s += __shfl_xor(s, off, 64);
    sq += __shfl_xor(sq, off, 64);
  }
  float mu = s * (1.0f / 256.0f);
  float var = fmaxf(sq * (1.0f / 256.0f) - mu * mu, 0.0f);
  float rs = rsqrtf(var + LN_EPS);
  if (half == 0) {
    uint4 o;
    unsigned* ou = &o.x;
#pragma unroll
    for (int k = 0; k < 4; ++k) {
      int c = l32 * 8 + 2 * k;
      float x0 = (vals[2 * k] - mu) * rs * ld1f(g, c, inf32) + ld1f(be, c, inf32);
      float x1 = (vals[2 * k + 1] - mu) * rs * ld1f(g, c + 1, inf32) + ld1f(be, c + 1, inf32);
      unsigned lo = f2bfbits(fmaxf(x0, 0.0f));
      unsigned hi = f2bfbits(fmaxf(x1, 0.0f));
      ou[k] = lo | (hi << 16);
    }
    *reinterpret_cast<uint4*>(out + (size_t)row * 256 + l32 * 8) = o;
  }
}

// ---- fused final: d_out = Yself + mean(Yn[nbrs]); D=128, quarter-wave gather ----
__global__ __launch_bounds__(256) void fused_out_kernel(
    const unsigned short* __restrict__ Yn, const float* __restrict__ Yself,
    const int* __restrict__ rowptr, const int* __restrict__ csr_src,
    const void* __restrict__ indeg, void* __restrict__ out,
    const int* __restrict__ dtflag) {
  bool inf32 = dtflag[0] != 0;
  int row = blockIdx.x * 4 + (threadIdx.x >> 6);
  int lane = threadIdx.x & 63;
  int qq = lane >> 4;
  int l16 = lane & 15;
  int beg = rowptr[row], end = rowptr[row + 1];
  float a[8] = {};
  for (int e = beg + qq; e < end; e += 4) {
    int s0 = csr_src[e];
    uint4 r0 = *reinterpret_cast<const uint4*>(Yn + (size_t)s0 * 128 + l16 * 8);
    const unsigned* u0 = &r0.x;
#pragma unroll
    for (int k = 0; k < 4; ++k) {
      a[2 * k] += bfbits2f((unsigned short)(u0[k] & 0xffff));
      a[2 * k + 1] += bfbits2f((unsigned short)(u0[k] >> 16));
    }
  }
#pragma unroll
  for (int k = 0; k < 8; ++k) {
    a[k] += __shfl_xor(a[k], 16, 64);
    a[k] += __shfl_xor(a[k], 32, 64);
  }
  if (qq == 0) {
    float rd = 1.0f / ld1f(indeg, row, inf32);
    size_t base = (size_t)row * 128 + l16 * 8;
    float4 y0 = *reinterpret_cast<const float4*>(Yself + base);
    float4 y1 = *reinterpret_cast<const float4*>(Yself + base + 4);
    float v[8] = {a[0] * rd + y0.x, a[1] * rd + y0.y, a[2] * rd + y0.z,
                  a[3] * rd + y0.w, a[4] * rd + y1.x, a[5] * rd + y1.y,
                  a[6] * rd + y1.z, a[7] * rd + y1.w};
    if (inf32) {
      float4 o0 = {v[0], v[1], v[2], v[3]};
      float4 o1 = {v[4], v[5], v[6], v[7]};
      *reinterpret_cast<float4*>((float*)out + base) = o0;
      *reinterpret_cast<float4*>((float*)out + base + 4) = o1;
    } else {
      uint4 o;
      unsigned* ou = &o.x;
#pragma unroll
      for (int k = 0; k < 4; ++k)
        ou[k] = (unsigned)f2bfbits(v[2 * k]) | ((unsigned)f2bfbits(v[2 * k + 1]) << 16);
      *reinterpret_cast<uint4*>((unsigned short*)out + base) = o;
    }
  }
}

extern "C" void kernel_launch(void* const* d_in, const int* in_sizes, int n_in,
                              void* d_out, int out_size, void* d_ws, size_t ws_size,
                              hipStream_t stream) {
  const void* feat = d_in[0];
  const int* ei = (const int*)d_in[1];
  const void* indeg = d_in[2];
  const void* ws0 = d_in[3]; const void* wn0 = d_in[4]; const void* b0 = d_in[5];
  const void* ws1 = d_in[6]; const void* wn1 = d_in[7]; const void* b1 = d_in[8];
  const void* ws2 = d_in[9]; const void* wn2 = d_in[10]; const void* b2 = d_in[11];
  const void* g0 = d_in[12]; const void* be0 = d_in[13];
  const void* g1 = d_in[14]; const void* be1 = d_in[15];
  const int* src = ei;
  const int* dst = ei + NE;

  unsigned short* featbf = (unsigned short*)d_ws;            // 25.6 MB
  unsigned short* hbf = featbf + (size_t)NN * 256;           // 25.6 MB
  unsigned short* Yn = hbf + (size_t)NN * 256;               // 25.6 MB
  float* Yself = (float*)(Yn + (size_t)NN * 256);            // 51.2 MB
  unsigned short* Bt0 = (unsigned short*)(Yself + (size_t)NN * 256);
  unsigned short* Bt1 = Bt0 + 512 * 256;
  unsigned short* Bt2 = Bt1 + 512 * 256;
  int* flag = (int*)(Bt2 + 256 * 256);
  int* bsum = flag + 4;
  int* boff = bsum + 256;
  int* counts = boff + 256;
  int* rowptr = counts + NN;
  int* cursor = rowptr + NN + 1;
  int* csr_src = cursor + NN;

  dim3 blk(256);
  dim3 gE((NE + 255) / 256);
  dim3 gRow(12500);

  detect_kernel<<<1, 64, 0, stream>>>(feat, flag);
  conv_feat_kernel<<<12500, blk, 0, stream>>>(feat, featbf, flag);
  conv_w_kernel<256><<<512, blk, 0, stream>>>(ws0, wn0, Bt0, flag);
  conv_w_kernel<256><<<512, blk, 0, stream>>>(ws1, wn1, Bt1, flag);
  conv_w_kernel<128><<<256, blk, 0, stream>>>(ws2, wn2, Bt2, flag);

  hipMemsetAsync(counts, 0, NN * sizeof(int), stream);
  count_kernel<<<gE, blk, 0, stream>>>(dst, counts);
  bsum_kernel<<<NBLK, blk, 0, stream>>>(counts, bsum);
  bscan_kernel<<<1, blk, 0, stream>>>(bsum, boff);
  rowptr_kernel<<<NBLK, blk, 0, stream>>>(counts, boff, rowptr, cursor);
  fill_kernel<<<gE, blk, 0, stream>>>(src, dst, cursor, csr_src);

  // layer 0
  gemm_pack_kernel<512><<<dim3(391, 4), blk, 0, stream>>>(featbf, Bt0, b0, Yself, Yn, flag);
  fused_ln_kernel<<<gRow, blk, 0, stream>>>(Yn, Yself, rowptr, csr_src, indeg, g0, be0, hbf, flag);
  // layer 1
  gemm_pack_kernel<512><<<dim3(391, 4), blk, 0, stream>>>(hbf, Bt1, b1, Yself, Yn, flag);
  fused_ln_kernel<<<gRow, blk, 0, stream>>>(Yn, Yself, rowptr, csr_src, indeg, g1, be1, hbf, flag);
  // layer 2 -> d_out
  gemm_pack_kernel<256><<<dim3(391, 2), blk, 0, stream>>>(hbf, Bt2, b2, Yself, Yn, flag);
  fused_out_kernel<<<gRow, blk, 0, stream>>>(Yn, Yself, rowptr, csr_src, indeg, d_out, flag);
}

// Round 8
// 545.304 us; speedup vs baseline: 1.0732x; 1.0301x over previous
//
#include <hip/hip_runtime.h>
#include <stdint.h>

#define NN 50000
#define NE 800000
#define LN_EPS 1e-5f
#define NBLK 196  // ceil(NN/256)

typedef __attribute__((ext_vector_type(8))) __bf16 bf16x8;
typedef __attribute__((ext_vector_type(4))) float floatx4;

#define GLD_LDS16(gp, lp)                                              \
  __builtin_amdgcn_global_load_lds(                                    \
      (const __attribute__((address_space(1))) unsigned int*)(gp),     \
      (__attribute__((address_space(3))) unsigned int*)(lp), 16, 0, 0)

__device__ __forceinline__ float bfbits2f(unsigned short u) {
  return __uint_as_float(((unsigned)u) << 16);
}
__device__ __forceinline__ unsigned short f2bfbits(float f) {
  unsigned u = __float_as_uint(f);
  u += 0x7FFFu + ((u >> 16) & 1u);   // round-to-nearest-even
  return (unsigned short)(u >> 16);
}
__device__ __forceinline__ float4 ld4f(const void* p, size_t i, bool f32) {
  if (f32) return *reinterpret_cast<const float4*>((const float*)p + i);
  ushort4 r = *reinterpret_cast<const ushort4*>((const unsigned short*)p + i);
  return make_float4(bfbits2f(r.x), bfbits2f(r.y), bfbits2f(r.z), bfbits2f(r.w));
}
__device__ __forceinline__ float ld1f(const void* p, size_t i, bool f32) {
  return f32 ? ((const float*)p)[i] : bfbits2f(((const unsigned short*)p)[i]);
}
__device__ __forceinline__ void acc8(float* a, uint4 r) {
  const unsigned* u = &r.x;
#pragma unroll
  for (int k = 0; k < 4; ++k) {
    a[2 * k] += bfbits2f((unsigned short)(u[k] & 0xffff));
    a[2 * k + 1] += bfbits2f((unsigned short)(u[k] >> 16));
  }
}

// fp32 vs bf16 input detection (fp32 read as bf16 halves -> huge/NaN values).
__global__ void detect_kernel(const void* feat, int* flag) {
  int cnt = 0;
  const unsigned short* u = (const unsigned short*)feat;
  for (int i = threadIdx.x; i < 512; i += 64) {
    float v = bfbits2f(u[i]);
    if (!(fabsf(v) < 1e6f)) cnt++;
  }
#pragma unroll
  for (int off = 32; off > 0; off >>= 1) cnt += __shfl_down(cnt, off, 64);
  if (threadIdx.x == 0) flag[0] = (cnt > 8) ? 1 : 0;
}

__global__ void conv_feat_kernel(const void* __restrict__ feat,
                                 unsigned short* __restrict__ featbf,
                                 const int* __restrict__ flag) {
  bool f32 = flag[0] != 0;
  size_t i = ((size_t)blockIdx.x * blockDim.x + threadIdx.x) * 4;
  float4 v = ld4f(feat, i, f32);
  ushort4 o = {f2bfbits(v.x), f2bfbits(v.y), f2bfbits(v.z), f2bfbits(v.w)};
  *reinterpret_cast<ushort4*>(featbf + i) = o;
}

// All three weight sets -> Bt[n][k] bf16 (n in [0,2D), k in [0,256)).
__global__ void conv_w_all_kernel(const void* __restrict__ ws0, const void* __restrict__ wn0,
                                  const void* __restrict__ ws1, const void* __restrict__ wn1,
                                  const void* __restrict__ ws2, const void* __restrict__ wn2,
                                  unsigned short* __restrict__ Bt0,  // Bt1, Bt2 contiguous after
                                  const int* __restrict__ flag) {
  bool f32 = flag[0] != 0;
  int t = blockIdx.x * blockDim.x + threadIdx.x;  // 0 .. 327679
  const void* wself;
  const void* wneigh;
  int D, loc;
  if (t < 131072) { wself = ws0; wneigh = wn0; D = 256; loc = t; }
  else if (t < 262144) { wself = ws1; wneigh = wn1; D = 256; loc = t - 131072; }
  else { wself = ws2; wneigh = wn2; D = 128; loc = t - 262144; }
  int k = loc & 255, n = loc >> 8;
  float v = (n < D) ? ld1f(wself, (size_t)k * D + n, f32)
                    : ld1f(wneigh, (size_t)k * D + (n - D), f32);
  Bt0[t] = f2bfbits(v);
}

// ---- CSR build ----
__global__ void count_kernel(const int* __restrict__ dst, int* __restrict__ counts) {
  int e = blockIdx.x * blockDim.x + threadIdx.x;
  if (e >= NE) return;
  atomicAdd(&counts[dst[e]], 1);
}

__global__ __launch_bounds__(256) void bsum_kernel(const int* __restrict__ counts,
                                                   int* __restrict__ bsum) {
  int i = blockIdx.x * 256 + threadIdx.x;
  int v = (i < NN) ? counts[i] : 0;
#pragma unroll
  for (int off = 32; off > 0; off >>= 1) v += __shfl_down(v, off, 64);
  __shared__ int w[4];
  if ((threadIdx.x & 63) == 0) w[threadIdx.x >> 6] = v;
  __syncthreads();
  if (threadIdx.x == 0) bsum[blockIdx.x] = w[0] + w[1] + w[2] + w[3];
}

__global__ __launch_bounds__(256) void bscan_kernel(const int* __restrict__ bsum,
                                                    int* __restrict__ boff) {
  __shared__ int sh[256];
  int tid = threadIdx.x;
  int v = (tid < NBLK) ? bsum[tid] : 0;
  sh[tid] = v;
  __syncthreads();
  for (int off = 1; off < 256; off <<= 1) {
    int t = (tid >= off) ? sh[tid - off] : 0;
    __syncthreads();
    sh[tid] += t;
    __syncthreads();
  }
  boff[tid] = sh[tid] - v;
}

__global__ __launch_bounds__(256) void rowptr_kernel(const int* __restrict__ counts,
                                                     const int* __restrict__ boff,
                                                     int* __restrict__ rowptr,
                                                     int* __restrict__ cursor) {
  __shared__ int sh[256];
  int tid = threadIdx.x;
  int i = blockIdx.x * 256 + tid;
  int v = (i < NN) ? counts[i] : 0;
  sh[tid] = v;
  __syncthreads();
  for (int off = 1; off < 256; off <<= 1) {
    int t = (tid >= off) ? sh[tid - off] : 0;
    __syncthreads();
    sh[tid] += t;
    __syncthreads();
  }
  int incl = sh[tid];
  int base = boff[blockIdx.x];
  if (i < NN) {
    int r = base + incl - v;
    rowptr[i] = r;
    cursor[i] = r;
  }
  if (i == NN - 1) rowptr[NN] = base + incl;
}

__global__ void fill_kernel(const int* __restrict__ src, const int* __restrict__ dst,
                            int* __restrict__ cursor, int* __restrict__ csr_src) {
  int e = blockIdx.x * blockDim.x + threadIdx.x;
  if (e >= NE) return;
  int pos = atomicAdd(&cursor[dst[e]], 1);
  csr_src[pos] = src[e];
}

// ---- MFMA GEMM: Y(bf16 [NN][2D]) = A(bf16 NNx256) @ Bt^T + [bias|0] ----
// 128x128 tile, BK=32, coalesced+swizzled global_load_lds staging (see R7).
template <int TWO_D>
__global__ __launch_bounds__(256) void gemm_pack_kernel(
    const unsigned short* __restrict__ A, const unsigned short* __restrict__ Bt,
    const void* __restrict__ bias, unsigned short* __restrict__ Y,
    const int* __restrict__ dtflag) {
  constexpr int D = TWO_D / 2;
  __shared__ unsigned short As[128 * 32];  // 8 KB
  __shared__ unsigned short Bs[128 * 32];
  const int tid = threadIdx.x;
  const int lane = tid & 63;
  const int wave = tid >> 6;
  const int row0 = blockIdx.x * 128;
  const int col0 = blockIdx.y * 128;
  const int wr = (wave >> 1) * 64;
  const int wc = (wave & 1) * 64;
  const int fr = lane & 15;
  const int q = lane >> 4;
  const int sw = (q ^ ((fr >> 1) & 3)) * 8;  // swizzled chunk offset (ushorts)

  floatx4 acc[4][4];
#pragma unroll
  for (int i = 0; i < 4; ++i)
#pragma unroll
    for (int j = 0; j < 4; ++j) acc[i][j] = (floatx4){0.f, 0.f, 0.f, 0.f};

  const int srow = tid >> 2;                          // 0..63
  const int gch = ((tid & 3) ^ ((tid >> 3) & 3)) * 8; // global chunk offset
  const size_t ga0 = (size_t)(row0 + srow) * 256 + gch;
  const size_t ga1 = (size_t)(row0 + srow + 64) * 256 + gch;
  const size_t gb0 = (size_t)(col0 + srow) * 256 + gch;
  const size_t gb1 = (size_t)(col0 + srow + 64) * 256 + gch;
  unsigned short* la0 = As + (tid & 192) * 8;           // wave-uniform bases
  unsigned short* la1 = As + ((tid & 192) + 256) * 8;
  unsigned short* lb0 = Bs + (tid & 192) * 8;
  unsigned short* lb1 = Bs + ((tid & 192) + 256) * 8;

  for (int kb = 0; kb < 256; kb += 32) {
    if (kb) __syncthreads();
    GLD_LDS16(A + ga0 + kb, la0);
    GLD_LDS16(A + ga1 + kb, la1);
    GLD_LDS16(Bt + gb0 + kb, lb0);
    GLD_LDS16(Bt + gb1 + kb, lb1);
    __syncthreads();
    bf16x8 af[4], bfr[4];
#pragma unroll
    for (int i = 0; i < 4; ++i)
      af[i] = *reinterpret_cast<const bf16x8*>(As + (wr + i * 16 + fr) * 32 + sw);
#pragma unroll
    for (int j = 0; j < 4; ++j)
      bfr[j] = *reinterpret_cast<const bf16x8*>(Bs + (wc + j * 16 + fr) * 32 + sw);
#pragma unroll
    for (int i = 0; i < 4; ++i)
#pragma unroll
      for (int j = 0; j < 4; ++j)
        acc[i][j] = __builtin_amdgcn_mfma_f32_16x16x32_bf16(af[i], bfr[j], acc[i][j], 0, 0, 0);
  }

  bool inf32 = dtflag[0] != 0;
#pragma unroll
  for (int j = 0; j < 4; ++j) {
    int gc = col0 + wc + j * 16 + fr;  // [0, TWO_D)
    float bj = (gc < D) ? ld1f(bias, gc, inf32) : 0.f;
#pragma unroll
    for (int i = 0; i < 4; ++i) {
      int rbase = row0 + wr + i * 16 + (lane >> 4) * 4;
#pragma unroll
      for (int r = 0; r < 4; ++r) {
        int gr = rbase + r;
        if (gr < NN) Y[(size_t)gr * TWO_D + gc] = f2bfbits(acc[i][j][r] + bj);
      }
    }
  }
}

// ---- fused: h = ReLU(LN(Yself + mean(Yneigh[nbrs]))), D=256 ----
// One wave/row; half-wave per edge (16B/lane); 8 edges in flight per wave.
__global__ __launch_bounds__(256) void fused_ln_kernel(
    const unsigned short* __restrict__ Y,  // [NN][512] bf16: self|neigh
    const int* __restrict__ rowptr, const int* __restrict__ csr_src,
    const void* __restrict__ indeg, const void* __restrict__ g,
    const void* __restrict__ be, unsigned short* __restrict__ out,
    const int* __restrict__ dtflag) {
  bool inf32 = dtflag[0] != 0;
  int row = blockIdx.x * 4 + (threadIdx.x >> 6);
  int lane = threadIdx.x & 63;
  int half = lane >> 5;
  int l32 = lane & 31;
  int beg = rowptr[row], end = rowptr[row + 1];
  float a[8] = {};
  const size_t noff = 256 + l32 * 8;  // neigh half, this lane's 8 cols
  int e = beg + half;
  for (; e + 6 < end; e += 8) {
    int s0 = csr_src[e], s1 = csr_src[e + 2], s2 = csr_src[e + 4], s3 = csr_src[e + 6];
    uint4 r0 = *reinterpret_cast<const uint4*>(Y + (size_t)s0 * 512 + noff);
    uint4 r1 = *reinterpret_cast<const uint4*>(Y + (size_t)s1 * 512 + noff);
    uint4 r2 = *reinterpret_cast<const uint4*>(Y + (size_t)s2 * 512 + noff);
    uint4 r3 = *reinterpret_cast<const uint4*>(Y + (size_t)s3 * 512 + noff);
    acc8(a, r0); acc8(a, r1); acc8(a, r2); acc8(a, r3);
  }
  for (; e < end; e += 2) {
    int s0 = csr_src[e];
    uint4 r0 = *reinterpret_cast<const uint4*>(Y + (size_t)s0 * 512 + noff);
    acc8(a, r0);
  }
#pragma unroll
  for (int k = 0; k < 8; ++k) a[k] += __shfl_xor(a[k], 32, 64);
  float rd = 1.0f / ld1f(indeg, row, inf32);
  uint4 ys = *reinterpret_cast<const uint4*>(Y + (size_t)row * 512 + l32 * 8);
  const unsigned* yu = &ys.x;
  float vals[8];
#pragma unroll
  for (int k = 0; k < 4; ++k) {
    vals[2 * k] = a[2 * k] * rd + bfbits2f((unsigned short)(yu[k] & 0xffff));
    vals[2 * k + 1] = a[2 * k + 1] * rd + bfbits2f((unsigned short)(yu[k] >> 16));
  }
  float s = 0.f, sq = 0.f;
#pragma unroll
  for (int k = 0; k < 8; ++k) { s += vals[k]; sq += vals[k] * vals[k]; }
#pragma unroll
  for (int off = 1; off < 32; off <<= 1) {
    s += __shfl_xor(s, off, 64);
    sq += __shfl_xor(sq, off, 64);
  }
  float mu = s * (1.0f / 256.0f);
  float var = fmaxf(sq * (1.0f / 256.0f) - mu * mu, 0.0f);
  float rs = rsqrtf(var + LN_EPS);
  if (half == 0) {
    uint4 o;
    unsigned* ou = &o.x;
#pragma unroll
    for (int k = 0; k < 4; ++k) {
      int c = l32 * 8 + 2 * k;
      float x0 = (vals[2 * k] - mu) * rs * ld1f(g, c, inf32) + ld1f(be, c, inf32);
      float x1 = (vals[2 * k + 1] - mu) * rs * ld1f(g, c + 1, inf32) + ld1f(be, c + 1, inf32);
      ou[k] = (unsigned)f2bfbits(fmaxf(x0, 0.0f)) | ((unsigned)f2bfbits(fmaxf(x1, 0.0f)) << 16);
    }
    *reinterpret_cast<uint4*>(out + (size_t)row * 256 + l32 * 8) = o;
  }
}

// ---- fused final: d_out = Yself + mean(Yneigh[nbrs]); D=128 ----
// Quarter-wave per edge; 8 edges in flight per wave.
__global__ __launch_bounds__(256) void fused_out_kernel(
    const unsigned short* __restrict__ Y,  // [NN][256] bf16: self|neigh
    const int* __restrict__ rowptr, const int* __restrict__ csr_src,
    const void* __restrict__ indeg, void* __restrict__ out,
    const int* __restrict__ dtflag) {
  bool inf32 = dtflag[0] != 0;
  int row = blockIdx.x * 4 + (threadIdx.x >> 6);
  int lane = threadIdx.x & 63;
  int qq = lane >> 4;
  int l16 = lane & 15;
  int beg = rowptr[row], end = rowptr[row + 1];
  float a[8] = {};
  const size_t noff = 128 + l16 * 8;
  int e = beg + qq;
  for (; e + 4 < end; e += 8) {
    int s0 = csr_src[e], s1 = csr_src[e + 4];
    uint4 r0 = *reinterpret_cast<const uint4*>(Y + (size_t)s0 * 256 + noff);
    uint4 r1 = *reinterpret_cast<const uint4*>(Y + (size_t)s1 * 256 + noff);
    acc8(a, r0); acc8(a, r1);
  }
  if (e < end) {
    uint4 r0 = *reinterpret_cast<const uint4*>(Y + (size_t)csr_src[e] * 256 + noff);
    acc8(a, r0);
  }
#pragma unroll
  for (int k = 0; k < 8; ++k) {
    a[k] += __shfl_xor(a[k], 16, 64);
    a[k] += __shfl_xor(a[k], 32, 64);
  }
  if (qq == 0) {
    float rd = 1.0f / ld1f(indeg, row, inf32);
    size_t base = (size_t)row * 128 + l16 * 8;
    uint4 ys = *reinterpret_cast<const uint4*>(Y + (size_t)row * 256 + l16 * 8);
    const unsigned* yu = &ys.x;
    float v[8];
#pragma unroll
    for (int k = 0; k < 4; ++k) {
      v[2 * k] = a[2 * k] * rd + bfbits2f((unsigned short)(yu[k] & 0xffff));
      v[2 * k + 1] = a[2 * k + 1] * rd + bfbits2f((unsigned short)(yu[k] >> 16));
    }
    if (inf32) {
      float4 o0 = {v[0], v[1], v[2], v[3]};
      float4 o1 = {v[4], v[5], v[6], v[7]};
      *reinterpret_cast<float4*>((float*)out + base) = o0;
      *reinterpret_cast<float4*>((float*)out + base + 4) = o1;
    } else {
      uint4 o;
      unsigned* ou = &o.x;
#pragma unroll
      for (int k = 0; k < 4; ++k)
        ou[k] = (unsigned)f2bfbits(v[2 * k]) | ((unsigned)f2bfbits(v[2 * k + 1]) << 16);
      *reinterpret_cast<uint4*>((unsigned short*)out + base) = o;
    }
  }
}

extern "C" void kernel_launch(void* const* d_in, const int* in_sizes, int n_in,
                              void* d_out, int out_size, void* d_ws, size_t ws_size,
                              hipStream_t stream) {
  const void* feat = d_in[0];
  const int* ei = (const int*)d_in[1];
  const void* indeg = d_in[2];
  const void* ws0 = d_in[3]; const void* wn0 = d_in[4]; const void* b0 = d_in[5];
  const void* ws1 = d_in[6]; const void* wn1 = d_in[7]; const void* b1 = d_in[8];
  const void* ws2 = d_in[9]; const void* wn2 = d_in[10]; const void* b2 = d_in[11];
  const void* g0 = d_in[12]; const void* be0 = d_in[13];
  const void* g1 = d_in[14]; const void* be1 = d_in[15];
  const int* src = ei;
  const int* dst = ei + NE;

  unsigned short* featbf = (unsigned short*)d_ws;            // 25.6 MB
  unsigned short* hbf = featbf + (size_t)NN * 256;           // 25.6 MB
  unsigned short* Y = hbf + (size_t)NN * 256;                // 51.2 MB ([NN][512])
  unsigned short* Bt0 = Y + (size_t)NN * 512;                // 3 weight sets, contiguous
  unsigned short* Bt1 = Bt0 + 512 * 256;
  unsigned short* Bt2 = Bt1 + 512 * 256;
  int* flag = (int*)(Bt2 + 256 * 256);
  int* bsum = flag + 4;
  int* boff = bsum + 256;
  int* counts = boff + 256;
  int* rowptr = counts + NN;
  int* cursor = rowptr + NN + 1;
  int* csr_src = cursor + NN;

  dim3 blk(256);
  dim3 gE((NE + 255) / 256);
  dim3 gRow(12500);

  detect_kernel<<<1, 64, 0, stream>>>(feat, flag);
  conv_feat_kernel<<<12500, blk, 0, stream>>>(feat, featbf, flag);
  conv_w_all_kernel<<<1280, blk, 0, stream>>>(ws0, wn0, ws1, wn1, ws2, wn2, Bt0, flag);

  hipMemsetAsync(counts, 0, NN * sizeof(int), stream);
  count_kernel<<<gE, blk, 0, stream>>>(dst, counts);
  bsum_kernel<<<NBLK, blk, 0, stream>>>(counts, bsum);
  bscan_kernel<<<1, blk, 0, stream>>>(bsum, boff);
  rowptr_kernel<<<NBLK, blk, 0, stream>>>(counts, boff, rowptr, cursor);
  fill_kernel<<<gE, blk, 0, stream>>>(src, dst, cursor, csr_src);

  // layer 0
  gemm_pack_kernel<512><<<dim3(391, 4), blk, 0, stream>>>(featbf, Bt0, b0, Y, flag);
  fused_ln_kernel<<<gRow, blk, 0, stream>>>(Y, rowptr, csr_src, indeg, g0, be0, hbf, flag);
  // layer 1
  gemm_pack_kernel<512><<<dim3(391, 4), blk, 0, stream>>>(hbf, Bt1, b1, Y, flag);
  fused_ln_kernel<<<gRow, blk, 0, stream>>>(Y, rowptr, csr_src, indeg, g1, be1, hbf, flag);
  // layer 2 -> d_out (Y reused as [NN][256])
  gemm_pack_kernel<256><<<dim3(391, 2), blk, 0, stream>>>(hbf, Bt2, b2, Y, flag);
  fused_out_kernel<<<gRow, blk, 0, stream>>>(Y, rowptr, csr_src, indeg, d_out, flag);
}

// Round 9
// 532.274 us; speedup vs baseline: 1.0994x; 1.0245x over previous
//
#include <hip/hip_runtime.h>
#include <stdint.h>

#define NN 50000
#define NE 800000
#define LN_EPS 1e-5f
#define NBLK 196  // ceil(NN/256)

typedef __attribute__((ext_vector_type(8))) __bf16 bf16x8;
typedef __attribute__((ext_vector_type(4))) float floatx4;
typedef __attribute__((ext_vector_type(2))) float floatx2;

#define GLD_LDS16(gp, lp)                                              \
  __builtin_amdgcn_global_load_lds(                                    \
      (const __attribute__((address_space(1))) unsigned int*)(gp),     \
      (__attribute__((address_space(3))) unsigned int*)(lp), 16, 0, 0)

__device__ __forceinline__ float bfbits2f(unsigned short u) {
  return __uint_as_float(((unsigned)u) << 16);
}
__device__ __forceinline__ unsigned short f2bfbits(float f) {
  unsigned u = __float_as_uint(f);
  u += 0x7FFFu + ((u >> 16) & 1u);   // round-to-nearest-even
  return (unsigned short)(u >> 16);
}
__device__ __forceinline__ unsigned char f2fp8(float f) {
  unsigned p = __builtin_amdgcn_cvt_pk_fp8_f32(f, f, 0, false);
  return (unsigned char)(p & 0xff);
}
// accumulate 16 fp8 (one uint4) into a[16] via HW cvt (2 elems/inst)
__device__ __forceinline__ void accf8(float* a, uint4 r) {
  const unsigned* u = &r.x;
#pragma unroll
  for (int k = 0; k < 4; ++k) {
    floatx2 lo = __builtin_amdgcn_cvt_pk_f32_fp8(u[k], false);
    floatx2 hi = __builtin_amdgcn_cvt_pk_f32_fp8(u[k], true);
    a[4 * k + 0] += lo[0]; a[4 * k + 1] += lo[1];
    a[4 * k + 2] += hi[0]; a[4 * k + 3] += hi[1];
  }
}
__device__ __forceinline__ float4 ld4f(const void* p, size_t i, bool f32) {
  if (f32) return *reinterpret_cast<const float4*>((const float*)p + i);
  ushort4 r = *reinterpret_cast<const ushort4*>((const unsigned short*)p + i);
  return make_float4(bfbits2f(r.x), bfbits2f(r.y), bfbits2f(r.z), bfbits2f(r.w));
}
__device__ __forceinline__ float ld1f(const void* p, size_t i, bool f32) {
  return f32 ? ((const float*)p)[i] : bfbits2f(((const unsigned short*)p)[i]);
}

// fp32 vs bf16 input detection (fp32 read as bf16 halves -> huge/NaN values).
__global__ void detect_kernel(const void* feat, int* flag) {
  int cnt = 0;
  const unsigned short* u = (const unsigned short*)feat;
  for (int i = threadIdx.x; i < 512; i += 64) {
    float v = bfbits2f(u[i]);
    if (!(fabsf(v) < 1e6f)) cnt++;
  }
#pragma unroll
  for (int off = 32; off > 0; off >>= 1) cnt += __shfl_down(cnt, off, 64);
  if (threadIdx.x == 0) flag[0] = (cnt > 8) ? 1 : 0;
}

__global__ void conv_feat_kernel(const void* __restrict__ feat,
                                 unsigned short* __restrict__ featbf,
                                 const int* __restrict__ flag) {
  bool f32 = flag[0] != 0;
  size_t i = ((size_t)blockIdx.x * blockDim.x + threadIdx.x) * 4;
  float4 v = ld4f(feat, i, f32);
  ushort4 o = {f2bfbits(v.x), f2bfbits(v.y), f2bfbits(v.z), f2bfbits(v.w)};
  *reinterpret_cast<ushort4*>(featbf + i) = o;
}

// All three weight sets -> Bt[n][k] bf16 (n in [0,2D), k in [0,256)).
__global__ void conv_w_all_kernel(const void* __restrict__ ws0, const void* __restrict__ wn0,
                                  const void* __restrict__ ws1, const void* __restrict__ wn1,
                                  const void* __restrict__ ws2, const void* __restrict__ wn2,
                                  unsigned short* __restrict__ Bt0,
                                  const int* __restrict__ flag) {
  bool f32 = flag[0] != 0;
  int t = blockIdx.x * blockDim.x + threadIdx.x;
  const void* wself;
  const void* wneigh;
  int D, loc;
  if (t < 131072) { wself = ws0; wneigh = wn0; D = 256; loc = t; }
  else if (t < 262144) { wself = ws1; wneigh = wn1; D = 256; loc = t - 131072; }
  else { wself = ws2; wneigh = wn2; D = 128; loc = t - 262144; }
  int k = loc & 255, n = loc >> 8;
  float v = (n < D) ? ld1f(wself, (size_t)k * D + n, f32)
                    : ld1f(wneigh, (size_t)k * D + (n - D), f32);
  Bt0[t] = f2bfbits(v);
}

// ---- CSR build ----
__global__ void count_kernel(const int* __restrict__ dst, int* __restrict__ counts) {
  int e = blockIdx.x * blockDim.x + threadIdx.x;
  if (e >= NE) return;
  atomicAdd(&counts[dst[e]], 1);
}

__global__ __launch_bounds__(256) void bsum_kernel(const int* __restrict__ counts,
                                                   int* __restrict__ bsum) {
  int i = blockIdx.x * 256 + threadIdx.x;
  int v = (i < NN) ? counts[i] : 0;
#pragma unroll
  for (int off = 32; off > 0; off >>= 1) v += __shfl_down(v, off, 64);
  __shared__ int w[4];
  if ((threadIdx.x & 63) == 0) w[threadIdx.x >> 6] = v;
  __syncthreads();
  if (threadIdx.x == 0) bsum[blockIdx.x] = w[0] + w[1] + w[2] + w[3];
}

__global__ __launch_bounds__(256) void bscan_kernel(const int* __restrict__ bsum,
                                                    int* __restrict__ boff) {
  __shared__ int sh[256];
  int tid = threadIdx.x;
  int v = (tid < NBLK) ? bsum[tid] : 0;
  sh[tid] = v;
  __syncthreads();
  for (int off = 1; off < 256; off <<= 1) {
    int t = (tid >= off) ? sh[tid - off] : 0;
    __syncthreads();
    sh[tid] += t;
    __syncthreads();
  }
  boff[tid] = sh[tid] - v;
}

__global__ __launch_bounds__(256) void rowptr_kernel(const int* __restrict__ counts,
                                                     const int* __restrict__ boff,
                                                     int* __restrict__ rowptr,
                                                     int* __restrict__ cursor) {
  __shared__ int sh[256];
  int tid = threadIdx.x;
  int i = blockIdx.x * 256 + tid;
  int v = (i < NN) ? counts[i] : 0;
  sh[tid] = v;
  __syncthreads();
  for (int off = 1; off < 256; off <<= 1) {
    int t = (tid >= off) ? sh[tid - off] : 0;
    __syncthreads();
    sh[tid] += t;
    __syncthreads();
  }
  int incl = sh[tid];
  int base = boff[blockIdx.x];
  if (i < NN) {
    int r = base + incl - v;
    rowptr[i] = r;
    cursor[i] = r;
  }
  if (i == NN - 1) rowptr[NN] = base + incl;
}

__global__ void fill_kernel(const int* __restrict__ src, const int* __restrict__ dst,
                            int* __restrict__ cursor, int* __restrict__ csr_src) {
  int e = blockIdx.x * blockDim.x + threadIdx.x;
  if (e >= NE) return;
  int pos = atomicAdd(&cursor[dst[e]], 1);
  csr_src[pos] = src[e];
}

// ---- MFMA GEMM: Yself(bf16)=A@Ws+bias, Yn(fp8)=A@Wn ----
// 128x128 tile, BK=32, coalesced+swizzled global_load_lds staging (R7).
template <int TWO_D>
__global__ __launch_bounds__(256) void gemm_pack_kernel(
    const unsigned short* __restrict__ A, const unsigned short* __restrict__ Bt,
    const void* __restrict__ bias, unsigned short* __restrict__ Yself,
    unsigned char* __restrict__ Yn, const int* __restrict__ dtflag) {
  constexpr int D = TWO_D / 2;
  __shared__ unsigned short As[128 * 32];  // 8 KB
  __shared__ unsigned short Bs[128 * 32];
  const int tid = threadIdx.x;
  const int lane = tid & 63;
  const int wave = tid >> 6;
  const int row0 = blockIdx.x * 128;
  const int col0 = blockIdx.y * 128;
  const int wr = (wave >> 1) * 64;
  const int wc = (wave & 1) * 64;
  const int fr = lane & 15;
  const int q = lane >> 4;
  const int sw = (q ^ ((fr >> 1) & 3)) * 8;

  floatx4 acc[4][4];
#pragma unroll
  for (int i = 0; i < 4; ++i)
#pragma unroll
    for (int j = 0; j < 4; ++j) acc[i][j] = (floatx4){0.f, 0.f, 0.f, 0.f};

  const int srow = tid >> 2;
  const int gch = ((tid & 3) ^ ((tid >> 3) & 3)) * 8;
  const size_t ga0 = (size_t)(row0 + srow) * 256 + gch;
  const size_t ga1 = (size_t)(row0 + srow + 64) * 256 + gch;
  const size_t gb0 = (size_t)(col0 + srow) * 256 + gch;
  const size_t gb1 = (size_t)(col0 + srow + 64) * 256 + gch;
  unsigned short* la0 = As + (tid & 192) * 8;
  unsigned short* la1 = As + ((tid & 192) + 256) * 8;
  unsigned short* lb0 = Bs + (tid & 192) * 8;
  unsigned short* lb1 = Bs + ((tid & 192) + 256) * 8;

  for (int kb = 0; kb < 256; kb += 32) {
    if (kb) __syncthreads();
    GLD_LDS16(A + ga0 + kb, la0);
    GLD_LDS16(A + ga1 + kb, la1);
    GLD_LDS16(Bt + gb0 + kb, lb0);
    GLD_LDS16(Bt + gb1 + kb, lb1);
    __syncthreads();
    bf16x8 af[4], bfr[4];
#pragma unroll
    for (int i = 0; i < 4; ++i)
      af[i] = *reinterpret_cast<const bf16x8*>(As + (wr + i * 16 + fr) * 32 + sw);
#pragma unroll
    for (int j = 0; j < 4; ++j)
      bfr[j] = *reinterpret_cast<const bf16x8*>(Bs + (wc + j * 16 + fr) * 32 + sw);
#pragma unroll
    for (int i = 0; i < 4; ++i)
#pragma unroll
      for (int j = 0; j < 4; ++j)
        acc[i][j] = __builtin_amdgcn_mfma_f32_16x16x32_bf16(af[i], bfr[j], acc[i][j], 0, 0, 0);
  }

  bool inf32 = dtflag[0] != 0;
#pragma unroll
  for (int j = 0; j < 4; ++j) {
    int gc = col0 + wc + j * 16 + fr;  // [0, TWO_D)
    bool self = gc < D;
    float bj = self ? ld1f(bias, gc, inf32) : 0.f;
#pragma unroll
    for (int i = 0; i < 4; ++i) {
      int rbase = row0 + wr + i * 16 + (lane >> 4) * 4;
#pragma unroll
      for (int r = 0; r < 4; ++r) {
        int gr = rbase + r;
        if (gr < NN) {
          float v = acc[i][j][r] + bj;
          if (self)
            Yself[(size_t)gr * D + gc] = f2bfbits(v);
          else
            Yn[(size_t)gr * D + gc - D] = f2fp8(v);
        }
      }
    }
  }
}

// ---- fused: h = ReLU(LN(Yself + mean(Yn[nbrs]))), D=256 ----
// 16 lanes/edge x 16B (16 fp8 cols); 4 edges concurrent/wave, unroll 2.
__global__ __launch_bounds__(256) void fused_ln_kernel(
    const unsigned char* __restrict__ Yn, const unsigned short* __restrict__ Yself,
    const int* __restrict__ rowptr, const int* __restrict__ csr_src,
    const void* __restrict__ indeg, const void* __restrict__ g,
    const void* __restrict__ be, unsigned short* __restrict__ out,
    const int* __restrict__ dtflag) {
  bool inf32 = dtflag[0] != 0;
  int row = blockIdx.x * 4 + (threadIdx.x >> 6);
  int lane = threadIdx.x & 63;
  int qq = lane >> 4;
  int l16 = lane & 15;
  int beg = rowptr[row], end = rowptr[row + 1];
  float a[16] = {};
  int e = beg + qq;
  for (; e + 4 < end; e += 8) {
    int s0 = csr_src[e], s1 = csr_src[e + 4];
    uint4 r0 = *reinterpret_cast<const uint4*>(Yn + (size_t)s0 * 256 + l16 * 16);
    uint4 r1 = *reinterpret_cast<const uint4*>(Yn + (size_t)s1 * 256 + l16 * 16);
    accf8(a, r0); accf8(a, r1);
  }
  if (e < end) {
    uint4 r0 = *reinterpret_cast<const uint4*>(Yn + (size_t)csr_src[e] * 256 + l16 * 16);
    accf8(a, r0);
  }
#pragma unroll
  for (int k = 0; k < 16; ++k) {
    a[k] += __shfl_xor(a[k], 16, 64);
    a[k] += __shfl_xor(a[k], 32, 64);
  }
  float rd = 1.0f / ld1f(indeg, row, inf32);
  uint4 ys0 = *reinterpret_cast<const uint4*>(Yself + (size_t)row * 256 + l16 * 16);
  uint4 ys1 = *reinterpret_cast<const uint4*>(Yself + (size_t)row * 256 + l16 * 16 + 8);
  const unsigned* y0 = &ys0.x;
  const unsigned* y1 = &ys1.x;
  float vals[16];
#pragma unroll
  for (int k = 0; k < 4; ++k) {
    vals[2 * k] = a[2 * k] * rd + bfbits2f((unsigned short)(y0[k] & 0xffff));
    vals[2 * k + 1] = a[2 * k + 1] * rd + bfbits2f((unsigned short)(y0[k] >> 16));
    vals[8 + 2 * k] = a[8 + 2 * k] * rd + bfbits2f((unsigned short)(y1[k] & 0xffff));
    vals[9 + 2 * k] = a[9 + 2 * k] * rd + bfbits2f((unsigned short)(y1[k] >> 16));
  }
  float s = 0.f, sq = 0.f;
#pragma unroll
  for (int k = 0; k < 16; ++k) { s += vals[k]; sq += vals[k] * vals[k]; }
#pragma unroll
  for (int off = 1; off < 16; off <<= 1) {
    s += __shfl_xor(s, off, 64);
    sq += __shfl_xor(sq, off, 64);
  }
  float mu = s * (1.0f / 256.0f);
  float var = fmaxf(sq * (1.0f / 256.0f) - mu * mu, 0.0f);
  float rs = rsqrtf(var + LN_EPS);
  if (qq == 0) {
    uint4 o0, o1;
    unsigned* u0 = &o0.x;
    unsigned* u1 = &o1.x;
#pragma unroll
    for (int k = 0; k < 4; ++k) {
      int c = l16 * 16 + 2 * k;
      float x0 = (vals[2 * k] - mu) * rs * ld1f(g, c, inf32) + ld1f(be, c, inf32);
      float x1 = (vals[2 * k + 1] - mu) * rs * ld1f(g, c + 1, inf32) + ld1f(be, c + 1, inf32);
      float x2 = (vals[8 + 2 * k] - mu) * rs * ld1f(g, c + 8, inf32) + ld1f(be, c + 8, inf32);
      float x3 = (vals[9 + 2 * k] - mu) * rs * ld1f(g, c + 9, inf32) + ld1f(be, c + 9, inf32);
      u0[k] = (unsigned)f2bfbits(fmaxf(x0, 0.f)) | ((unsigned)f2bfbits(fmaxf(x1, 0.f)) << 16);
      u1[k] = (unsigned)f2bfbits(fmaxf(x2, 0.f)) | ((unsigned)f2bfbits(fmaxf(x3, 0.f)) << 16);
    }
    *reinterpret_cast<uint4*>(out + (size_t)row * 256 + l16 * 16) = o0;
    *reinterpret_cast<uint4*>(out + (size_t)row * 256 + l16 * 16 + 8) = o1;
  }
}

// ---- fused final: d_out = Yself + mean(Yn[nbrs]); D=128 ----
// 8 lanes/edge x 16B; 8 edges concurrent/wave, unroll 2.
__global__ __launch_bounds__(256) void fused_out_kernel(
    const unsigned char* __restrict__ Yn, const unsigned short* __restrict__ Yself,
    const int* __restrict__ rowptr, const int* __restrict__ csr_src,
    const void* __restrict__ indeg, void* __restrict__ out,
    const int* __restrict__ dtflag) {
  bool inf32 = dtflag[0] != 0;
  int row = blockIdx.x * 4 + (threadIdx.x >> 6);
  int lane = threadIdx.x & 63;
  int oo = lane >> 3;   // 0..7
  int l8 = lane & 7;
  int beg = rowptr[row], end = rowptr[row + 1];
  float a[16] = {};
  int e = beg + oo;
  for (; e + 8 < end; e += 16) {
    int s0 = csr_src[e], s1 = csr_src[e + 8];
    uint4 r0 = *reinterpret_cast<const uint4*>(Yn + (size_t)s0 * 128 + l8 * 16);
    uint4 r1 = *reinterpret_cast<const uint4*>(Yn + (size_t)s1 * 128 + l8 * 16);
    accf8(a, r0); accf8(a, r1);
  }
  if (e < end) {
    uint4 r0 = *reinterpret_cast<const uint4*>(Yn + (size_t)csr_src[e] * 128 + l8 * 16);
    accf8(a, r0);
  }
#pragma unroll
  for (int k = 0; k < 16; ++k) {
    a[k] += __shfl_xor(a[k], 8, 64);
    a[k] += __shfl_xor(a[k], 16, 64);
    a[k] += __shfl_xor(a[k], 32, 64);
  }
  if (oo == 0) {
    float rd = 1.0f / ld1f(indeg, row, inf32);
    uint4 ys0 = *reinterpret_cast<const uint4*>(Yself + (size_t)row * 128 + l8 * 16);
    uint4 ys1 = *reinterpret_cast<const uint4*>(Yself + (size_t)row * 128 + l8 * 16 + 8);
    const unsigned* y0 = &ys0.x;
    const unsigned* y1 = &ys1.x;
    float v[16];
#pragma unroll
    for (int k = 0; k < 4; ++k) {
      v[2 * k] = a[2 * k] * rd + bfbits2f((unsigned short)(y0[k] & 0xffff));
      v[2 * k + 1] = a[2 * k + 1] * rd + bfbits2f((unsigned short)(y0[k] >> 16));
      v[8 + 2 * k] = a[8 + 2 * k] * rd + bfbits2f((unsigned short)(y1[k] & 0xffff));
      v[9 + 2 * k] = a[9 + 2 * k] * rd + bfbits2f((unsigned short)(y1[k] >> 16));
    }
    size_t base = (size_t)row * 128 + l8 * 16;
    if (inf32) {
#pragma unroll
      for (int p = 0; p < 4; ++p) {
        float4 o = {v[4 * p], v[4 * p + 1], v[4 * p + 2], v[4 * p + 3]};
        *reinterpret_cast<float4*>((float*)out + base + 4 * p) = o;
      }
    } else {
      uint4 o0, o1;
      unsigned* u0 = &o0.x;
      unsigned* u1 = &o1.x;
#pragma unroll
      for (int k = 0; k < 4; ++k) {
        u0[k] = (unsigned)f2bfbits(v[2 * k]) | ((unsigned)f2bfbits(v[2 * k + 1]) << 16);
        u1[k] = (unsigned)f2bfbits(v[8 + 2 * k]) | ((unsigned)f2bfbits(v[9 + 2 * k]) << 16);
      }
      *reinterpret_cast<uint4*>((unsigned short*)out + base) = o0;
      *reinterpret_cast<uint4*>((unsigned short*)out + base + 8) = o1;
    }
  }
}

extern "C" void kernel_launch(void* const* d_in, const int* in_sizes, int n_in,
                              void* d_out, int out_size, void* d_ws, size_t ws_size,
                              hipStream_t stream) {
  const void* feat = d_in[0];
  const int* ei = (const int*)d_in[1];
  const void* indeg = d_in[2];
  const void* ws0 = d_in[3]; const void* wn0 = d_in[4]; const void* b0 = d_in[5];
  const void* ws1 = d_in[6]; const void* wn1 = d_in[7]; const void* b1 = d_in[8];
  const void* ws2 = d_in[9]; const void* wn2 = d_in[10]; const void* b2 = d_in[11];
  const void* g0 = d_in[12]; const void* be0 = d_in[13];
  const void* g1 = d_in[14]; const void* be1 = d_in[15];
  const int* src = ei;
  const int* dst = ei + NE;

  unsigned short* featbf = (unsigned short*)d_ws;            // 25.6 MB
  unsigned short* hbf = featbf + (size_t)NN * 256;           // 25.6 MB
  unsigned short* Yself = hbf + (size_t)NN * 256;            // 25.6 MB bf16 [NN][256]
  unsigned char* Yn = (unsigned char*)(Yself + (size_t)NN * 256);  // 12.8 MB fp8 [NN][256]
  unsigned short* Bt0 = (unsigned short*)(Yn + (size_t)NN * 256);
  unsigned short* Bt1 = Bt0 + 512 * 256;
  unsigned short* Bt2 = Bt1 + 512 * 256;
  int* flag = (int*)(Bt2 + 256 * 256);
  int* bsum = flag + 4;
  int* boff = bsum + 256;
  int* counts = boff + 256;
  int* rowptr = counts + NN;
  int* cursor = rowptr + NN + 1;
  int* csr_src = cursor + NN;

  dim3 blk(256);
  dim3 gE((NE + 255) / 256);
  dim3 gRow(12500);

  detect_kernel<<<1, 64, 0, stream>>>(feat, flag);
  conv_feat_kernel<<<12500, blk, 0, stream>>>(feat, featbf, flag);
  conv_w_all_kernel<<<1280, blk, 0, stream>>>(ws0, wn0, ws1, wn1, ws2, wn2, Bt0, flag);

  hipMemsetAsync(counts, 0, NN * sizeof(int), stream);
  count_kernel<<<gE, blk, 0, stream>>>(dst, counts);
  bsum_kernel<<<NBLK, blk, 0, stream>>>(counts, bsum);
  bscan_kernel<<<1, blk, 0, stream>>>(bsum, boff);
  rowptr_kernel<<<NBLK, blk, 0, stream>>>(counts, boff, rowptr, cursor);
  fill_kernel<<<gE, blk, 0, stream>>>(src, dst, cursor, csr_src);

  // layer 0
  gemm_pack_kernel<512><<<dim3(391, 4), blk, 0, stream>>>(featbf, Bt0, b0, Yself, Yn, flag);
  fused_ln_kernel<<<gRow, blk, 0, stream>>>(Yn, Yself, rowptr, csr_src, indeg, g0, be0, hbf, flag);
  // layer 1
  gemm_pack_kernel<512><<<dim3(391, 4), blk, 0, stream>>>(hbf, Bt1, b1, Yself, Yn, flag);
  fused_ln_kernel<<<gRow, blk, 0, stream>>>(Yn, Yself, rowptr, csr_src, indeg, g1, be1, hbf, flag);
  // layer 2 -> d_out (Yself/Yn reused at D=128)
  gemm_pack_kernel<256><<<dim3(391, 2), blk, 0, stream>>>(hbf, Bt2, b2, Yself, Yn, flag);
  fused_out_kernel<<<gRow, blk, 0, stream>>>(Yn, Yself, rowptr, csr_src, indeg, d_out, flag);
}